// Round 4
// baseline (354.925 us; speedup 1.0000x reference)
//
#include <hip/hip_runtime.h>
#include <hip/hip_bf16.h>

typedef __attribute__((ext_vector_type(8))) short short8;
typedef __attribute__((ext_vector_type(4))) float float4v;
typedef __attribute__((ext_vector_type(4))) unsigned int uint4v;

#define DDIM 1024

__device__ __forceinline__ unsigned short f2bf(float f) {
  unsigned u = __builtin_bit_cast(unsigned, f);
  unsigned r = (u + 0x7fffu + ((u >> 16) & 1u)) >> 16;   // RNE
  return (unsigned short)r;
}
__device__ __forceinline__ unsigned pk2(float lo, float hi) {
  return (unsigned)f2bf(lo) | ((unsigned)f2bf(hi) << 16);
}
__device__ __forceinline__ void cvt8(const float* src, unsigned short* dst) {
  float4v a = *(const float4v*)(src);
  float4v b = *(const float4v*)(src + 4);
  uint4v pk;
  pk.x = pk2(a.x, a.y); pk.y = pk2(a.z, a.w);
  pk.z = pk2(b.x, b.y); pk.w = pk2(b.z, b.w);
  *(uint4v*)dst = pk;
}
// hw packed convert: 1 VALU op for 2 floats (RNE). Compiler cannot derive this
// from the bit-math form; inline asm required (no builtin on gfx950).
__device__ __forceinline__ unsigned cvtpk(float lo, float hi) {
  unsigned r;
  asm("v_cvt_pk_bf16_f32 %0, %1, %2" : "=v"(r) : "v"(lo), "v"(hi));
  return r;
}

// ---- prepass: W only (1M elems) fp32 -> bf16 ----
__global__ __launch_bounds__(256) void convert_w(const float* __restrict__ W,
                                                 unsigned short* __restrict__ Wb) {
  size_t i = ((size_t)blockIdx.x * 256 + threadIdx.x) * 8;
  cvt8(W + i, Wb + i);
}

// ---- fused main: 128 rows x 128 d-cols per block, K=1024 ----
// XCD-locality remap: mg=(b&7)|((b>>6)<<3), dt=(b>>3)&7 -> the 8 d-tile blocks
// of one m-group share bid%8 (same XCD) and sit in a 57-bid window -> eth slice
// fetched once, L2-reused 8x (verified: FETCH 336->160 MB, rounds 2-3).
// eth fp32 read directly (no prepass): global->reg, v_cvt_pk_bf16_f32, swizzled
// ds_write (round 4: bit-math cvt was ~160 VALU/iter on the barrier path).
// W on the global_load_lds DMA path, depth-2 counted vmcnt.
// launch_bounds (256,3): 170 regs/wave -- (256,4)/128 spilled (round 2).
__global__ __launch_bounds__(256, 3) void bilinear_fused(const float* __restrict__ elg,
                                                         const float* __restrict__ eth,
                                                         const unsigned short* __restrict__ Wb,
                                                         float* __restrict__ out) {
  __shared__ unsigned short Wbuf[2][128 * 32];  // 16 KB
  __shared__ unsigned short ethL[2][128 * 32];  // 16 KB (bf16 after cvt)
  __shared__ float wsum[4][64];                 // 1 KB

  const int tid  = threadIdx.x;
  const int lane = tid & 63;
  const int w    = tid >> 6;
  const int quad = lane >> 4;
  const int l15  = lane & 15;
  const int rowhalf = w >> 1;
  const int colhalf = w & 1;
  const int b  = blockIdx.x;
  const int mg = (b & 7) | ((b >> 6) << 3);   // m-group 0..255
  const int dt = (b >> 3) & 7;                // d-tile 0..7
  const int m0 = mg * 128;
  const int d0 = dt * 128;
  const int wr = lane >> 2, wu = lane & 3;    // W-DMA row/unit role

  // eth reg-stage roles: thread t -> row t>>1, 16 consecutive floats (2 units)
  const int er = tid >> 1;
  const int eh = tid & 1;
  const int es = (er >> 1) & 3;               // same XOR swizzle as reader
  const float* ebase = eth + (size_t)(m0 + er) * DDIM + eh * 16;
  const int eslotA = ((2 * eh + 0) ^ es) * 8;
  const int eslotB = ((2 * eh + 1) ^ es) * 8;

  // W stage: 2 DMA instrs/thread, 8 KB
  auto stage_w = [&](int ek, int buf) {
    const int e0 = ek * 32;
#pragma unroll
    for (int j = 0; j < 2; ++j) {
      const int R0 = w * 16 + j * 64;
      const int r  = R0 + wr;
      const int ug = wu ^ ((r >> 1) & 3);     // swizzle on the GLOBAL side
      const unsigned short* gw = Wb + (size_t)(d0 + r) * DDIM + e0 + ug * 8;
      unsigned short* lw = &Wbuf[buf][R0 * 32 + lane * 8];
      __builtin_amdgcn_global_load_lds(
          (const __attribute__((address_space(1))) unsigned int*)gw,
          (__attribute__((address_space(3))) unsigned int*)lw, 16, 0, 0);
    }
  };

  float4v e0v, e1v, e2v, e3v;                 // eth(k+1) staging regs
  auto load_E = [&](int ek) {
    const float* p = ebase + ek * 32;
    e0v = *(const float4v*)(p);
    e1v = *(const float4v*)(p + 4);
    e2v = *(const float4v*)(p + 8);
    e3v = *(const float4v*)(p + 12);
  };
  auto write_E = [&](int buf) {
    uint4v pa, pb;
    pa.x = cvtpk(e0v.x, e0v.y); pa.y = cvtpk(e0v.z, e0v.w);
    pa.z = cvtpk(e1v.x, e1v.y); pa.w = cvtpk(e1v.z, e1v.w);
    pb.x = cvtpk(e2v.x, e2v.y); pb.y = cvtpk(e2v.z, e2v.w);
    pb.z = cvtpk(e3v.x, e3v.y); pb.w = cvtpk(e3v.z, e3v.w);
    *(uint4v*)&ethL[buf][er * 32 + eslotA] = pa;
    *(uint4v*)&ethL[buf][er * 32 + eslotB] = pb;
  };

  float4v acc[4][4];
#pragma unroll
  for (int ct = 0; ct < 4; ++ct)
#pragma unroll
    for (int rt = 0; rt < 4; ++rt)
      acc[ct][rt] = (float4v){0.f, 0.f, 0.f, 0.f};

  // ---- prologue: buf0 fully ready; E(1) in regs; W(1) in flight to buf1 ----
  load_E(0);                                   // E0 x4
  asm volatile("" ::: "memory");               // pin issue order for counts
  stage_w(0, 0);                               // W0 x2
  asm volatile("" ::: "memory");
  write_E(0);                                  // compiler waits E0
  load_E(1);                                   // E1 x4
  asm volatile("" ::: "memory");
  stage_w(1, 1);                               // W1 x2
  asm volatile("s_waitcnt vmcnt(6)" ::: "memory");   // W0 landed (E1,W1 in flight)
  asm volatile("s_waitcnt lgkmcnt(0)" ::: "memory"); // my eth0 writes visible
  __builtin_amdgcn_s_barrier();

  for (int ek = 0; ek < 32; ++ek) {
    const int cur = ek & 1;
    // eth(ek+1) -> buf[cur^1] (all waves finished reading it last iter)
    if (ek < 31) write_E(cur ^ 1);             // auto-wait drains E(ek+1)
    if (ek < 30) load_E(ek + 2);               // issue early; lands next iter

    short8 aF[4], bF[4];
#pragma unroll
    for (int rt = 0; rt < 4; ++rt) {           // A[m=l15][k=quad*8+j]
      int r  = rowhalf * 64 + rt * 16 + l15;
      int pu = quad ^ ((r >> 1) & 3);
      aF[rt] = *(const short8*)&ethL[cur][r * 32 + pu * 8];
    }
#pragma unroll
    for (int ct = 0; ct < 4; ++ct) {           // B[k][n=l15] = W row d
      int r  = colhalf * 64 + ct * 16 + l15;
      int pu = quad ^ ((r >> 1) & 3);
      bF[ct] = *(const short8*)&Wbuf[cur][r * 32 + pu * 8];
    }
    asm volatile("s_waitcnt lgkmcnt(0)" ::: "memory");  // reads + my writes retired
    if (ek < 31) {
      __builtin_amdgcn_s_barrier();            // all waves done with buf[cur]
      asm volatile("" ::: "memory");
      if (ek < 30) {
        stage_w(ek + 2, cur);                  // refill W into freed buf
        asm volatile("s_waitcnt vmcnt(6)" ::: "memory"); // W(ek+1) landed
      } else {
        asm volatile("s_waitcnt vmcnt(0)" ::: "memory"); // drain W(31)
      }
      __builtin_amdgcn_s_barrier();            // buf[cur^1] fully ready
    }

    __builtin_amdgcn_s_setprio(1);
#pragma unroll
    for (int ct = 0; ct < 4; ++ct)
#pragma unroll
      for (int rt = 0; rt < 4; ++rt)
        acc[ct][rt] = __builtin_amdgcn_mfma_f32_16x16x32_bf16(aF[rt], bF[ct], acc[ct][rt], 0, 0, 0);
    __builtin_amdgcn_s_setprio(0);
  }

  // fused epilogue: p[m] = sum_col elg[m][col] * u[m][col] over this d-tile
  float p[16];
#pragma unroll
  for (int j = 0; j < 16; ++j) p[j] = 0.f;
#pragma unroll
  for (int ct = 0; ct < 4; ++ct) {
    int col = d0 + colhalf * 64 + ct * 16 + l15;
#pragma unroll
    for (int rt = 0; rt < 4; ++rt) {
      const float* ep = elg + (size_t)(m0 + rowhalf * 64 + rt * 16 + quad * 4) * DDIM + col;
#pragma unroll
      for (int i = 0; i < 4; ++i)
        p[rt * 4 + i] += acc[ct][rt][i] * ep[(size_t)i * DDIM];
    }
  }
#pragma unroll
  for (int off = 1; off < 16; off <<= 1)       // sum the 16 col-lanes per row
#pragma unroll
    for (int j = 0; j < 16; ++j)
      p[j] += __shfl_xor(p[j], off);
  if (l15 == 0) {
#pragma unroll
    for (int rt = 0; rt < 4; ++rt)
#pragma unroll
      for (int i = 0; i < 4; ++i)
        wsum[w][rt * 16 + quad * 4 + i] = p[rt * 4 + i];
  }
  __syncthreads();
  if (tid < 128) {
    int local = tid & 63, half = tid >> 6;
    float s = wsum[half * 2][local] + wsum[half * 2 + 1][local];
    atomicAdd(&out[m0 + tid], s);              // 8 d-tile blocks per output
  }
}

extern "C" void kernel_launch(void* const* d_in, const int* in_sizes, int n_in,
                              void* d_out, int out_size, void* d_ws, size_t ws_size,
                              hipStream_t stream) {
  (void)in_sizes; (void)n_in; (void)ws_size;
  const float* elg = (const float*)d_in[0];
  const float* eth = (const float*)d_in[1];
  const float* W   = (const float*)d_in[2];
  float* out = (float*)d_out;
  unsigned short* Wb = (unsigned short*)d_ws;  // 2 MB

  hipMemsetAsync(d_out, 0, (size_t)out_size * sizeof(float), stream);
  convert_w<<<dim3(512), dim3(256), 0, stream>>>(W, Wb);
  bilinear_fused<<<dim3(2048), dim3(256), 0, stream>>>(elg, eth, Wb, out);
}

// Round 5
// 337.189 us; speedup vs baseline: 1.0526x; 1.0526x over previous
//
#include <hip/hip_runtime.h>
#include <hip/hip_bf16.h>

typedef __attribute__((ext_vector_type(8))) short short8;
typedef __attribute__((ext_vector_type(4))) float float4v;
typedef __attribute__((ext_vector_type(4))) unsigned int uint4v;

#define DDIM 1024

__device__ __forceinline__ unsigned short f2bf(float f) {
  unsigned u = __builtin_bit_cast(unsigned, f);
  unsigned r = (u + 0x7fffu + ((u >> 16) & 1u)) >> 16;   // RNE
  return (unsigned short)r;
}
__device__ __forceinline__ unsigned pk2(float lo, float hi) {
  return (unsigned)f2bf(lo) | ((unsigned)f2bf(hi) << 16);
}
__device__ __forceinline__ void cvt8(const float* src, unsigned short* dst) {
  float4v a = *(const float4v*)(src);
  float4v b = *(const float4v*)(src + 4);
  uint4v pk;
  pk.x = pk2(a.x, a.y); pk.y = pk2(a.z, a.w);
  pk.z = pk2(b.x, b.y); pk.w = pk2(b.z, b.w);
  *(uint4v*)dst = pk;
}

// ---- prepass: W (1M) + eth (32M) fp32 -> bf16 in workspace ----
__global__ __launch_bounds__(256) void convert_all(const float* __restrict__ W,
                                                   const float* __restrict__ eth,
                                                   unsigned short* __restrict__ Wb,
                                                   unsigned short* __restrict__ ethB) {
  int b = blockIdx.x;
  if (b < 512) {
    size_t i = ((size_t)b * 256 + threadIdx.x) * 8;
    cvt8(W + i, Wb + i);
  } else {
    size_t i = ((size_t)(b - 512) * 256 + threadIdx.x) * 8;
    cvt8(eth + i, ethB + i);
  }
}
__global__ __launch_bounds__(256) void convert_w(const float* __restrict__ W,
                                                 unsigned short* __restrict__ Wb) {
  size_t i = ((size_t)blockIdx.x * 256 + threadIdx.x) * 8;
  cvt8(W + i, Wb + i);
}

// ---- main: 128 rows x 128 d-cols per block, K=1024, depth-2 counted-vmcnt pipe ----
// (round-1 proven structure, 116 us) + XCD-locality remap (rounds 2-4 verified:
// FETCH 336 -> 157 MB). mg=(b&7)|((b>>6)<<3), dt=(b>>3)&7: the 8 d-tile blocks
// of one m-group share bid%8 (same XCD, round-robin) and sit in a 57-bid window
// -> their 256 KB ethB slice is fetched once and L2-reused 8x; W (2 MB bf16)
// stays L2-resident per XCD. LDS 33 KB -> 4 blocks/CU.
// K-loop: raw s_barrier + counted s_waitcnt vmcnt(4) -- tile k+1's DMAs stay in
// flight across the whole iter; no vmcnt(0) drain in the loop body.
__global__ __launch_bounds__(256, 4) void bilinear_bf16(const float* __restrict__ elg,
                                                        const unsigned short* __restrict__ ethB,
                                                        const unsigned short* __restrict__ Wb,
                                                        float* __restrict__ out) {
  __shared__ unsigned short Wbuf[2][128 * 32];  // 16 KB
  __shared__ unsigned short ethL[2][128 * 32];  // 16 KB
  __shared__ float wsum[4][64];                 // 1 KB

  const int tid  = threadIdx.x;
  const int lane = tid & 63;
  const int w    = tid >> 6;
  const int quad = lane >> 4;
  const int l15  = lane & 15;
  const int rowhalf = w >> 1;       // wave's 64-row half
  const int colhalf = w & 1;        // wave's 64-col half
  const int b  = blockIdx.x;
  const int mg = (b & 7) | ((b >> 6) << 3);   // m-group 0..255
  const int dt = (b >> 3) & 7;                // d-tile 0..7
  const int m0 = mg * 128;
  const int d0 = dt * 128;
  const int wr = lane >> 2, wu = lane & 3;   // DMA row/unit role

  // stage K-chunk ek into buffer buf: 4 DMA instrs/thread, 16 KB total
  auto stage = [&](int ek, int buf) {
    const int e0 = ek * 32;
#pragma unroll
    for (int j = 0; j < 2; ++j) {
      const int R0 = w * 16 + j * 64;        // 16-row slab per wave-instr
      const int r  = R0 + wr;
      const int ug = wu ^ ((r >> 1) & 3);    // swizzle on the GLOBAL side
      const unsigned short* gw = Wb   + (size_t)(d0 + r) * DDIM + e0 + ug * 8;
      const unsigned short* ge = ethB + (size_t)(m0 + r) * DDIM + e0 + ug * 8;
      unsigned short* lw = &Wbuf[buf][R0 * 32 + lane * 8];
      unsigned short* le = &ethL[buf][R0 * 32 + lane * 8];
      __builtin_amdgcn_global_load_lds(
          (const __attribute__((address_space(1))) unsigned int*)gw,
          (__attribute__((address_space(3))) unsigned int*)lw, 16, 0, 0);
      __builtin_amdgcn_global_load_lds(
          (const __attribute__((address_space(1))) unsigned int*)ge,
          (__attribute__((address_space(3))) unsigned int*)le, 16, 0, 0);
    }
  };

  float4v acc[4][4];
#pragma unroll
  for (int ct = 0; ct < 4; ++ct)
#pragma unroll
    for (int rt = 0; rt < 4; ++rt)
      acc[ct][rt] = (float4v){0.f, 0.f, 0.f, 0.f};

  // depth-2 prologue: tiles 0 and 1 in flight (8 DMAs/thread outstanding)
  stage(0, 0);
  stage(1, 1);

  for (int ek = 0; ek < 32; ++ek) {
    const int cur = ek & 1;
    // tile ek's 4 DMAs are the oldest outstanding; leave tile ek+1's in flight
    if (ek < 31) asm volatile("s_waitcnt vmcnt(4)" ::: "memory");
    else         asm volatile("s_waitcnt vmcnt(0)" ::: "memory");
    __builtin_amdgcn_s_barrier();            // all waves: buf[cur] fully landed

    short8 aF[4], bF[4];
#pragma unroll
    for (int rt = 0; rt < 4; ++rt) {         // A[m=l15][k=quad*8+j]
      int r  = rowhalf * 64 + rt * 16 + l15;
      int pu = quad ^ ((r >> 1) & 3);
      aF[rt] = *(const short8*)&ethL[cur][r * 32 + pu * 8];
    }
#pragma unroll
    for (int ct = 0; ct < 4; ++ct) {         // B[k][n=l15] = W row d
      int r  = colhalf * 64 + ct * 16 + l15;
      int pu = quad ^ ((r >> 1) & 3);
      bF[ct] = *(const short8*)&Wbuf[cur][r * 32 + pu * 8];
    }
    asm volatile("s_waitcnt lgkmcnt(0)" ::: "memory");  // my reads of buf[cur] retired
    __builtin_amdgcn_s_barrier();            // all waves' reads retired -> cur free
    if (ek < 30) stage(ek + 2, cur);         // refill cur; overlaps MFMA + next wait

    __builtin_amdgcn_s_setprio(1);
#pragma unroll
    for (int ct = 0; ct < 4; ++ct)
#pragma unroll
      for (int rt = 0; rt < 4; ++rt)
        acc[ct][rt] = __builtin_amdgcn_mfma_f32_16x16x32_bf16(aF[rt], bF[ct], acc[ct][rt], 0, 0, 0);
    __builtin_amdgcn_s_setprio(0);
  }

  // fused epilogue: p[m] = sum_col elg[m][col] * u[m][col] over this d-tile
  float p[16];
#pragma unroll
  for (int j = 0; j < 16; ++j) p[j] = 0.f;
#pragma unroll
  for (int ct = 0; ct < 4; ++ct) {
    int col = d0 + colhalf * 64 + ct * 16 + l15;
#pragma unroll
    for (int rt = 0; rt < 4; ++rt) {
      const float* ep = elg + (size_t)(m0 + rowhalf * 64 + rt * 16 + quad * 4) * DDIM + col;
#pragma unroll
      for (int i = 0; i < 4; ++i)
        p[rt * 4 + i] += acc[ct][rt][i] * ep[(size_t)i * DDIM];
    }
  }
#pragma unroll
  for (int off = 1; off < 16; off <<= 1)     // sum the 16 col-lanes per row
#pragma unroll
    for (int j = 0; j < 16; ++j)
      p[j] += __shfl_xor(p[j], off);
  if (l15 == 0) {
#pragma unroll
    for (int rt = 0; rt < 4; ++rt)
#pragma unroll
      for (int i = 0; i < 4; ++i)
        wsum[w][rt * 16 + quad * 4 + i] = p[rt * 4 + i];   // local row in half
  }
  __syncthreads();
  if (tid < 128) {
    int local = tid & 63, half = tid >> 6;
    float s = wsum[half * 2][local] + wsum[half * 2 + 1][local];
    atomicAdd(&out[m0 + tid], s);            // 8 d-tile blocks per output
  }
}

// ---- fallback (ws too small for eth_bf16): round-2 proven kernel ----
#define ETH_STRIDE 40
__global__ __launch_bounds__(256, 3) void bilinear_fp32eth(const float* __restrict__ elg,
                                                           const float* __restrict__ eth,
                                                           const unsigned short* __restrict__ Wb,
                                                           float* __restrict__ out) {
  __shared__ unsigned short ethL[64 * ETH_STRIDE];
  __shared__ unsigned short Wbuf[256 * 32];
  __shared__ float wsum[4][64];
  const int tid  = threadIdx.x;
  const int lane = tid & 63;
  const int w    = tid >> 6;
  const int quad = lane >> 4;
  const int l15  = lane & 15;
  const int m0   = (blockIdx.x >> 2) * 64;
  const int d0   = (blockIdx.x & 3) * 256;
  const int erow = tid >> 2, eunit = tid & 3;
  const float* esrc = eth + (size_t)(m0 + erow) * DDIM + eunit * 8;
  const int wr = lane >> 2, wu = lane & 3;
  float4v er0 = *(const float4v*)(esrc);
  float4v er1 = *(const float4v*)(esrc + 4);
  float4v acc[4][4];
#pragma unroll
  for (int ct = 0; ct < 4; ++ct)
#pragma unroll
    for (int rt = 0; rt < 4; ++rt)
      acc[ct][rt] = (float4v){0.f, 0.f, 0.f, 0.f};
  for (int ek = 0; ek < 32; ++ek) {
    const int e0 = ek * 32;
    __syncthreads();
    {
      uint4v pk;
      pk.x = pk2(er0.x, er0.y); pk.y = pk2(er0.z, er0.w);
      pk.z = pk2(er1.x, er1.y); pk.w = pk2(er1.z, er1.w);
      *(uint4v*)&ethL[erow * ETH_STRIDE + eunit * 8] = pk;
    }
#pragma unroll
    for (int j = 0; j < 4; ++j) {
      int r  = (w * 4 + j) * 16 + wr;
      int ug = wu ^ ((r >> 1) & 3);
      const unsigned short* gp = Wb + (size_t)(d0 + r) * DDIM + e0 + ug * 8;
      unsigned short* lp = &Wbuf[(w * 4 + j) * 512 + lane * 8];
      __builtin_amdgcn_global_load_lds(
          (const __attribute__((address_space(1))) unsigned int*)gp,
          (__attribute__((address_space(3))) unsigned int*)lp, 16, 0, 0);
    }
    __syncthreads();
    short8 aF[4], bF[4];
#pragma unroll
    for (int rt = 0; rt < 4; ++rt)
      aF[rt] = *(const short8*)&ethL[(rt * 16 + l15) * ETH_STRIDE + quad * 8];
#pragma unroll
    for (int ct = 0; ct < 4; ++ct) {
      int dl = w * 64 + ct * 16 + l15;
      int pu = quad ^ ((dl >> 1) & 3);
      bF[ct] = *(const short8*)&Wbuf[dl * 32 + pu * 8];
    }
    if (ek < 31) {
      const float* s = esrc + (e0 + 32);
      er0 = *(const float4v*)(s);
      er1 = *(const float4v*)(s + 4);
    }
#pragma unroll
    for (int ct = 0; ct < 4; ++ct)
#pragma unroll
      for (int rt = 0; rt < 4; ++rt)
        acc[ct][rt] = __builtin_amdgcn_mfma_f32_16x16x32_bf16(aF[rt], bF[ct], acc[ct][rt], 0, 0, 0);
  }
  float p[16];
#pragma unroll
  for (int j = 0; j < 16; ++j) p[j] = 0.f;
#pragma unroll
  for (int ct = 0; ct < 4; ++ct) {
    int col = d0 + w * 64 + ct * 16 + l15;
#pragma unroll
    for (int rt = 0; rt < 4; ++rt) {
      const float* ep = elg + (size_t)(m0 + rt * 16 + quad * 4) * DDIM + col;
#pragma unroll
      for (int i = 0; i < 4; ++i)
        p[rt * 4 + i] += acc[ct][rt][i] * ep[(size_t)i * DDIM];
    }
  }
#pragma unroll
  for (int off = 1; off < 16; off <<= 1)
#pragma unroll
    for (int j = 0; j < 16; ++j)
      p[j] += __shfl_xor(p[j], off);
  if (l15 == 0) {
#pragma unroll
    for (int rt = 0; rt < 4; ++rt)
#pragma unroll
      for (int i = 0; i < 4; ++i)
        wsum[w][rt * 16 + quad * 4 + i] = p[rt * 4 + i];
  }
  __syncthreads();
  if (tid < 64) {
    float s = wsum[0][tid] + wsum[1][tid] + wsum[2][tid] + wsum[3][tid];
    atomicAdd(&out[m0 + tid], s);
  }
}

extern "C" void kernel_launch(void* const* d_in, const int* in_sizes, int n_in,
                              void* d_out, int out_size, void* d_ws, size_t ws_size,
                              hipStream_t stream) {
  (void)in_sizes; (void)n_in;
  const float* elg = (const float*)d_in[0];
  const float* eth = (const float*)d_in[1];
  const float* W   = (const float*)d_in[2];
  float* out = (float*)d_out;
  unsigned short* Wb   = (unsigned short*)d_ws;                      // 2 MB
  unsigned short* ethB = (unsigned short*)((char*)d_ws + (2 << 20)); // 64 MB

  const size_t need = (2ull << 20) + (64ull << 20);
  hipMemsetAsync(d_out, 0, (size_t)out_size * sizeof(float), stream);
  if (ws_size >= need) {
    convert_all<<<dim3(512 + 16384), dim3(256), 0, stream>>>(W, eth, Wb, ethB);
    bilinear_bf16<<<dim3(2048), dim3(256), 0, stream>>>(elg, ethB, Wb, out);
  } else {
    convert_w<<<dim3(512), dim3(256), 0, stream>>>(W, Wb);
    bilinear_fp32eth<<<dim3(2048), dim3(256), 0, stream>>>(elg, eth, Wb, out);
  }
}

// Round 6
// 336.129 us; speedup vs baseline: 1.0559x; 1.0032x over previous
//
#include <hip/hip_runtime.h>
#include <hip/hip_bf16.h>

typedef __attribute__((ext_vector_type(8))) short short8;
typedef __attribute__((ext_vector_type(4))) float float4v;
typedef __attribute__((ext_vector_type(4))) unsigned int uint4v;

#define DDIM 1024

__device__ __forceinline__ unsigned short f2bf(float f) {
  unsigned u = __builtin_bit_cast(unsigned, f);
  unsigned r = (u + 0x7fffu + ((u >> 16) & 1u)) >> 16;   // RNE
  return (unsigned short)r;
}
__device__ __forceinline__ unsigned pk2(float lo, float hi) {
  return (unsigned)f2bf(lo) | ((unsigned)f2bf(hi) << 16);
}
__device__ __forceinline__ void cvt8(const float* src, unsigned short* dst) {
  float4v a = *(const float4v*)(src);
  float4v b = *(const float4v*)(src + 4);
  uint4v pk;
  pk.x = pk2(a.x, a.y); pk.y = pk2(a.z, a.w);
  pk.z = pk2(b.x, b.y); pk.w = pk2(b.z, b.w);
  *(uint4v*)dst = pk;
}

// ---- prepass: W (1M) + eth (32M) fp32 -> bf16 in workspace ----
__global__ __launch_bounds__(256) void convert_all(const float* __restrict__ W,
                                                   const float* __restrict__ eth,
                                                   unsigned short* __restrict__ Wb,
                                                   unsigned short* __restrict__ ethB) {
  int b = blockIdx.x;
  if (b < 512) {
    size_t i = ((size_t)b * 256 + threadIdx.x) * 8;
    cvt8(W + i, Wb + i);
  } else {
    size_t i = ((size_t)(b - 512) * 256 + threadIdx.x) * 8;
    cvt8(eth + i, ethB + i);
  }
}
__global__ __launch_bounds__(256) void convert_w(const float* __restrict__ W,
                                                 unsigned short* __restrict__ Wb) {
  size_t i = ((size_t)blockIdx.x * 256 + threadIdx.x) * 8;
  cvt8(W + i, Wb + i);
}

// ---- main: 128 rows x 128 d-cols per block, K=1024, depth-2 counted-vmcnt pipe ----
// XCD remap (verified: FETCH 336->126 MB): mg=(b&7)|((b>>6)<<3), dt=(b>>3)&7.
// Round 6: K-phase STAGGER. Co-resident blocks on a CU (bids differing by 256
// under round-robin dispatch) run identical code and hit the barrier/vmcnt
// lockstep -- all 16 waves stall together (measured: 3975 cyc/iter vs ~1150
// L2-bound). The K-sum is order-independent, so each block starts its chunk
// sweep at koff=((b>>8)&3)*8: co-resident blocks' MFMA/stage phases interleave
// instead of colliding, and setprio(1) finally has roles to arbitrate (T5).
// If the CU-mapping assumption is wrong, offsets collapse to equal = status quo.
__global__ __launch_bounds__(256, 4) void bilinear_bf16(const float* __restrict__ elg,
                                                        const unsigned short* __restrict__ ethB,
                                                        const unsigned short* __restrict__ Wb,
                                                        float* __restrict__ out) {
  __shared__ unsigned short Wbuf[2][128 * 32];  // 16 KB
  __shared__ unsigned short ethL[2][128 * 32];  // 16 KB
  __shared__ float wsum[4][64];                 // 1 KB

  const int tid  = threadIdx.x;
  const int lane = tid & 63;
  const int w    = tid >> 6;
  const int quad = lane >> 4;
  const int l15  = lane & 15;
  const int rowhalf = w >> 1;       // wave's 64-row half
  const int colhalf = w & 1;        // wave's 64-col half
  const int b  = blockIdx.x;
  const int mg = (b & 7) | ((b >> 6) << 3);   // m-group 0..255
  const int dt = (b >> 3) & 7;                // d-tile 0..7
  const int m0 = mg * 128;
  const int d0 = dt * 128;
  const int koff = ((b >> 8) & 3) * 8;        // per-CU-slot K-phase stagger
  const int wr = lane >> 2, wu = lane & 3;    // DMA row/unit role

  // stage K-chunk ek into buffer buf: 4 DMA instrs/thread, 16 KB total
  auto stage = [&](int ek, int buf) {
    const int e0 = ek * 32;
#pragma unroll
    for (int j = 0; j < 2; ++j) {
      const int R0 = w * 16 + j * 64;        // 16-row slab per wave-instr
      const int r  = R0 + wr;
      const int ug = wu ^ ((r >> 1) & 3);    // swizzle on the GLOBAL side
      const unsigned short* gw = Wb   + (size_t)(d0 + r) * DDIM + e0 + ug * 8;
      const unsigned short* ge = ethB + (size_t)(m0 + r) * DDIM + e0 + ug * 8;
      unsigned short* lw = &Wbuf[buf][R0 * 32 + lane * 8];
      unsigned short* le = &ethL[buf][R0 * 32 + lane * 8];
      __builtin_amdgcn_global_load_lds(
          (const __attribute__((address_space(1))) unsigned int*)gw,
          (__attribute__((address_space(3))) unsigned int*)lw, 16, 0, 0);
      __builtin_amdgcn_global_load_lds(
          (const __attribute__((address_space(1))) unsigned int*)ge,
          (__attribute__((address_space(3))) unsigned int*)le, 16, 0, 0);
    }
  };

  float4v acc[4][4];
#pragma unroll
  for (int ct = 0; ct < 4; ++ct)
#pragma unroll
    for (int rt = 0; rt < 4; ++rt)
      acc[ct][rt] = (float4v){0.f, 0.f, 0.f, 0.f};

  // depth-2 prologue: tiles i=0,1 (chunks koff, koff+1) in flight
  stage(koff, 0);
  stage((koff + 1) & 31, 1);

  for (int i = 0; i < 32; ++i) {
    const int ek  = (i + koff) & 31;         // this block's chunk order
    const int cur = i & 1;
    // chunk ek's 4 DMAs are the oldest outstanding; leave next chunk's in flight
    if (i < 31) asm volatile("s_waitcnt vmcnt(4)" ::: "memory");
    else        asm volatile("s_waitcnt vmcnt(0)" ::: "memory");
    __builtin_amdgcn_s_barrier();            // all waves: buf[cur] fully landed

    short8 aF[4], bF[4];
#pragma unroll
    for (int rt = 0; rt < 4; ++rt) {         // A[m=l15][k=quad*8+j]
      int r  = rowhalf * 64 + rt * 16 + l15;
      int pu = quad ^ ((r >> 1) & 3);
      aF[rt] = *(const short8*)&ethL[cur][r * 32 + pu * 8];
    }
#pragma unroll
    for (int ct = 0; ct < 4; ++ct) {         // B[k][n=l15] = W row d
      int r  = colhalf * 64 + ct * 16 + l15;
      int pu = quad ^ ((r >> 1) & 3);
      bF[ct] = *(const short8*)&Wbuf[cur][r * 32 + pu * 8];
    }
    asm volatile("s_waitcnt lgkmcnt(0)" ::: "memory");  // my reads of buf[cur] retired
    __builtin_amdgcn_s_barrier();            // all waves' reads retired -> cur free
    if (i < 30) stage((i + 2 + koff) & 31, cur);  // refill cur; overlaps MFMA

    __builtin_amdgcn_s_setprio(1);
#pragma unroll
    for (int ct = 0; ct < 4; ++ct)
#pragma unroll
      for (int rt = 0; rt < 4; ++rt)
        acc[ct][rt] = __builtin_amdgcn_mfma_f32_16x16x32_bf16(aF[rt], bF[ct], acc[ct][rt], 0, 0, 0);
    __builtin_amdgcn_s_setprio(0);
  }

  // fused epilogue: p[m] = sum_col elg[m][col] * u[m][col] over this d-tile
  float p[16];
#pragma unroll
  for (int j = 0; j < 16; ++j) p[j] = 0.f;
#pragma unroll
  for (int ct = 0; ct < 4; ++ct) {
    int col = d0 + colhalf * 64 + ct * 16 + l15;
#pragma unroll
    for (int rt = 0; rt < 4; ++rt) {
      const float* ep = elg + (size_t)(m0 + rowhalf * 64 + rt * 16 + quad * 4) * DDIM + col;
#pragma unroll
      for (int i = 0; i < 4; ++i)
        p[rt * 4 + i] += acc[ct][rt][i] * ep[(size_t)i * DDIM];
    }
  }
#pragma unroll
  for (int off = 1; off < 16; off <<= 1)     // sum the 16 col-lanes per row
#pragma unroll
    for (int j = 0; j < 16; ++j)
      p[j] += __shfl_xor(p[j], off);
  if (l15 == 0) {
#pragma unroll
    for (int rt = 0; rt < 4; ++rt)
#pragma unroll
      for (int i = 0; i < 4; ++i)
        wsum[w][rt * 16 + quad * 4 + i] = p[rt * 4 + i];   // local row in half
  }
  __syncthreads();
  if (tid < 128) {
    int local = tid & 63, half = tid >> 6;
    float s = wsum[half * 2][local] + wsum[half * 2 + 1][local];
    atomicAdd(&out[m0 + tid], s);            // 8 d-tile blocks per output
  }
}

// ---- fallback (ws too small for eth_bf16): round-2 proven kernel ----
#define ETH_STRIDE 40
__global__ __launch_bounds__(256, 3) void bilinear_fp32eth(const float* __restrict__ elg,
                                                           const float* __restrict__ eth,
                                                           const unsigned short* __restrict__ Wb,
                                                           float* __restrict__ out) {
  __shared__ unsigned short ethL[64 * ETH_STRIDE];
  __shared__ unsigned short Wbuf[256 * 32];
  __shared__ float wsum[4][64];
  const int tid  = threadIdx.x;
  const int lane = tid & 63;
  const int w    = tid >> 6;
  const int quad = lane >> 4;
  const int l15  = lane & 15;
  const int m0   = (blockIdx.x >> 2) * 64;
  const int d0   = (blockIdx.x & 3) * 256;
  const int erow = tid >> 2, eunit = tid & 3;
  const float* esrc = eth + (size_t)(m0 + erow) * DDIM + eunit * 8;
  const int wr = lane >> 2, wu = lane & 3;
  float4v er0 = *(const float4v*)(esrc);
  float4v er1 = *(const float4v*)(esrc + 4);
  float4v acc[4][4];
#pragma unroll
  for (int ct = 0; ct < 4; ++ct)
#pragma unroll
    for (int rt = 0; rt < 4; ++rt)
      acc[ct][rt] = (float4v){0.f, 0.f, 0.f, 0.f};
  for (int ek = 0; ek < 32; ++ek) {
    const int e0 = ek * 32;
    __syncthreads();
    {
      uint4v pk;
      pk.x = pk2(er0.x, er0.y); pk.y = pk2(er0.z, er0.w);
      pk.z = pk2(er1.x, er1.y); pk.w = pk2(er1.z, er1.w);
      *(uint4v*)&ethL[erow * ETH_STRIDE + eunit * 8] = pk;
    }
#pragma unroll
    for (int j = 0; j < 4; ++j) {
      int r  = (w * 4 + j) * 16 + wr;
      int ug = wu ^ ((r >> 1) & 3);
      const unsigned short* gp = Wb + (size_t)(d0 + r) * DDIM + e0 + ug * 8;
      unsigned short* lp = &Wbuf[(w * 4 + j) * 512 + lane * 8];
      __builtin_amdgcn_global_load_lds(
          (const __attribute__((address_space(1))) unsigned int*)gp,
          (__attribute__((address_space(3))) unsigned int*)lp, 16, 0, 0);
    }
    __syncthreads();
    short8 aF[4], bF[4];
#pragma unroll
    for (int rt = 0; rt < 4; ++rt)
      aF[rt] = *(const short8*)&ethL[(rt * 16 + l15) * ETH_STRIDE + quad * 8];
#pragma unroll
    for (int ct = 0; ct < 4; ++ct) {
      int dl = w * 64 + ct * 16 + l15;
      int pu = quad ^ ((dl >> 1) & 3);
      bF[ct] = *(const short8*)&Wbuf[dl * 32 + pu * 8];
    }
    if (ek < 31) {
      const float* s = esrc + (e0 + 32);
      er0 = *(const float4v*)(s);
      er1 = *(const float4v*)(s + 4);
    }
#pragma unroll
    for (int ct = 0; ct < 4; ++ct)
#pragma unroll
      for (int rt = 0; rt < 4; ++rt)
        acc[ct][rt] = __builtin_amdgcn_mfma_f32_16x16x32_bf16(aF[rt], bF[ct], acc[ct][rt], 0, 0, 0);
  }
  float p[16];
#pragma unroll
  for (int j = 0; j < 16; ++j) p[j] = 0.f;
#pragma unroll
  for (int ct = 0; ct < 4; ++ct) {
    int col = d0 + w * 64 + ct * 16 + l15;
#pragma unroll
    for (int rt = 0; rt < 4; ++rt) {
      const float* ep = elg + (size_t)(m0 + rt * 16 + quad * 4) * DDIM + col;
#pragma unroll
      for (int i = 0; i < 4; ++i)
        p[rt * 4 + i] += acc[ct][rt][i] * ep[(size_t)i * DDIM];
    }
  }
#pragma unroll
  for (int off = 1; off < 16; off <<= 1)
#pragma unroll
    for (int j = 0; j < 16; ++j)
      p[j] += __shfl_xor(p[j], off);
  if (l15 == 0) {
#pragma unroll
    for (int rt = 0; rt < 4; ++rt)
#pragma unroll
      for (int i = 0; i < 4; ++i)
        wsum[w][rt * 16 + quad * 4 + i] = p[rt * 4 + i];
  }
  __syncthreads();
  if (tid < 64) {
    float s = wsum[0][tid] + wsum[1][tid] + wsum[2][tid] + wsum[3][tid];
    atomicAdd(&out[m0 + tid], s);
  }
}

extern "C" void kernel_launch(void* const* d_in, const int* in_sizes, int n_in,
                              void* d_out, int out_size, void* d_ws, size_t ws_size,
                              hipStream_t stream) {
  (void)in_sizes; (void)n_in;
  const float* elg = (const float*)d_in[0];
  const float* eth = (const float*)d_in[1];
  const float* W   = (const float*)d_in[2];
  float* out = (float*)d_out;
  unsigned short* Wb   = (unsigned short*)d_ws;                      // 2 MB
  unsigned short* ethB = (unsigned short*)((char*)d_ws + (2 << 20)); // 64 MB

  const size_t need = (2ull << 20) + (64ull << 20);
  hipMemsetAsync(d_out, 0, (size_t)out_size * sizeof(float), stream);
  if (ws_size >= need) {
    convert_all<<<dim3(512 + 16384), dim3(256), 0, stream>>>(W, eth, Wb, ethB);
    bilinear_bf16<<<dim3(2048), dim3(256), 0, stream>>>(elg, ethB, Wb, out);
  } else {
    convert_w<<<dim3(512), dim3(256), 0, stream>>>(W, Wb);
    bilinear_fp32eth<<<dim3(2048), dim3(256), 0, stream>>>(elg, eth, Wb, out);
  }
}